// Round 1
// 327.754 us; speedup vs baseline: 1.0074x; 1.0074x over previous
//
#include <hip/hip_runtime.h>

// out[b, n, d] = (n == 0 ? x_class[d] : inputs[b, n-1, d]) + embeddings[n, d]
// B=64, N=1024, D=768. Pure streaming triad, memory-bound.
//
// Layout (float4 units): for fixed b, the n>=1 bulk is CONTIGUOUS:
//   out4[b*196800 + 192 + i] = in4[b*196608 + i] + emb4[192 + i], i in [0,196608)
//
// Grid: exactly 2048 bulk blocks = 8 blocks/CU x 256 CUs -> ONE dispatch round,
// no second half-empty round (old grid: 3136 blocks = 1.53 rounds).
// Each block owns a contiguous 6144-f4 chunk; b = blockIdx.x >> 5, chunk = x & 31.
// All 64 b-copies of chunk c are 32 block-ids apart -> same XCD (32 % 8 == 0),
// so each emb chunk is HBM-fetched by one XCD only (~3 MB total, was ~25 MB).
//
// 2-deep software pipeline (batch-2), rolled loop, __launch_bounds__(256,8):
// ~48 VGPRs -> guaranteed 8 blocks/CU = 32 waves/CU, short vmcnt clauses
// (stores don't queue behind 16 outstanding loads like the old full unroll-16).
//
// Nontemporal on in/out (touched once) keeps L2 for the 64x-reused emb table.

typedef float f4 __attribute__((ext_vector_type(4)));

#define D4        192              // 768 / 4
#define ROWS4     196800           // 1025 * 192 (per-b out stride, f4 units)
#define BULK4     196608           // 1024 * 192 (per-b in stride, f4 units)
#define NB        64
#define BULK_BLKS 2048             // 8 blocks/CU * 256 CUs; 32 blocks per b
#define PER_BLK   6144             // BULK4 * NB / BULK_BLKS = 24 * 256
#define STEPS     12               // PER_BLK / (256 * 2)

__global__ __launch_bounds__(256, 8)
void pos_embed_kernel(const f4* __restrict__ in4,    // [64*196608]
                      const f4* __restrict__ cls4,   // [192]
                      const f4* __restrict__ emb4,   // [1025*192]
                      f4* __restrict__ out4) {       // [64*196800]
    const int x = blockIdx.x;

    if (x >= BULK_BLKS) {
        // cls row: out[b,0,:] = x_class + emb[0,:]   (64 tiny tail blocks)
        const int b = x - BULK_BLKS;
        const int t = threadIdx.x;
        if (t < D4) {
            out4[(size_t)b * ROWS4 + t] = cls4[t] + emb4[t];
        }
        return;
    }

    const int b  = x >> 5;                         // 32 blocks per b
    const int c  = x & 31;                         // chunk within b
    const int i0 = c * PER_BLK + threadIdx.x;      // within-b bulk f4 offset

    const f4* __restrict__ ip = in4  + (size_t)b * BULK4 + i0;
    const f4* __restrict__ ep = emb4 + D4 + i0;
    f4*       __restrict__ op = out4 + (size_t)b * ROWS4 + D4 + i0;

    // software pipeline: batch of 2 f4 per stage, 2 stages in flight
    f4 a0 = __builtin_nontemporal_load(ip);
    f4 a1 = __builtin_nontemporal_load(ip + 256);
    f4 e0 = ep[0];
    f4 e1 = ep[256];

    for (int k = 0; k < STEPS - 1; ++k) {
        const int cur = k * 512;
        const int nxt = cur + 512;
        f4 b0 = __builtin_nontemporal_load(ip + nxt);
        f4 b1 = __builtin_nontemporal_load(ip + nxt + 256);
        f4 f0 = ep[nxt];
        f4 f1 = ep[nxt + 256];
        f4 r0 = a0 + e0;
        f4 r1 = a1 + e1;
        __builtin_nontemporal_store(r0, op + cur);
        __builtin_nontemporal_store(r1, op + cur + 256);
        a0 = b0; a1 = b1; e0 = f0; e1 = f1;
    }
    {
        const int cur = (STEPS - 1) * 512;
        __builtin_nontemporal_store(a0 + e0, op + cur);
        __builtin_nontemporal_store(a1 + e1, op + cur + 256);
    }
}

extern "C" void kernel_launch(void* const* d_in, const int* in_sizes, int n_in,
                              void* d_out, int out_size, void* d_ws, size_t ws_size,
                              hipStream_t stream) {
    const f4* in4  = (const f4*)d_in[0];  // inputs [64,1024,768]
    const f4* cls4 = (const f4*)d_in[1];  // x_class [768]
    const f4* emb4 = (const f4*)d_in[2];  // embeddings [1025,768]
    f4* out4       = (f4*)d_out;          // [64,1025,768]

    dim3 grid(BULK_BLKS + NB, 1, 1);
    dim3 block(256, 1, 1);
    pos_embed_kernel<<<grid, block, 0, stream>>>(in4, cls4, emb4, out4);
}